// Round 4
// baseline (550.712 us; speedup 1.0000x reference)
//
#include <hip/hip_runtime.h>

#define B_    32
#define S_    577
#define HID_  768
#define NH_   12
#define HD_   64
#define SPAD  640
#define SB_   5            // s-blocks of 128 per batch (5*128 = 640)
#define MT_   160          // b-aligned m-tiles: 32 * 5
#define KT_   12           // 768/64
#define NT_   18           // 2304/128 (B-image panels)

typedef __attribute__((ext_vector_type(8))) short short8;
typedef __attribute__((ext_vector_type(4))) short short4s;
typedef __attribute__((ext_vector_type(4))) float float4_;

static __device__ __forceinline__ float bf2f(short s) {
    union { float f; unsigned u; } cvt;
    cvt.u = ((unsigned)(unsigned short)s) << 16;
    return cvt.f;
}
static __device__ __forceinline__ short f2bf(float f) {
    union { float f; unsigned u; } cvt;
    cvt.f = f;
    unsigned u = cvt.u;
    unsigned r = u + 0x7FFF + ((u >> 16) & 1);   // RNE; finite inputs
    return (short)(r >> 16);
}

// ---------------------------------------------------------------------------
// A image: ximg[mt=b*5+sb][kt][kg8][row128][8]  (MFMA-fragment-ordered bf16)
// ---------------------------------------------------------------------------
__global__ __launch_bounds__(256) void convA_kernel(
    const float* __restrict__ X, short* __restrict__ ximg)
{
    const int mt = blockIdx.x, kt = blockIdx.y;
    const int b = mt / SB_, sb = mt - b * SB_;
    short* img = ximg + ((size_t)mt * KT_ + kt) * 8192;
#pragma unroll
    for (int i = 0; i < 4; ++i) {
        const int j = i * 256 + threadIdx.x;   // 0..1023
        const int row = j >> 3, kg = j & 7;
        const int s = sb * 128 + row;
        const int srow = (s < S_) ? s : 0;     // pad rows: any finite
        const float* src = X + ((size_t)b * S_ + srow) * HID_ + kt * 64 + kg * 8;
        float4_ f0 = *(const float4_*)src;
        float4_ f1 = *(const float4_*)(src + 4);
        short8 s8;
#pragma unroll
        for (int e = 0; e < 4; ++e) { s8[e] = f2bf(f0[e]); s8[e + 4] = f2bf(f1[e]); }
        *(short8*)(img + ((size_t)kg * 128 + row) * 8) = s8;
    }
}

// B image: wimg[nt18][kt][kg8][row128][8], nt = z*6 + local (row = n in tile)
__global__ __launch_bounds__(256) void convB_kernel(
    const float* __restrict__ Wq, const float* __restrict__ Wk,
    const float* __restrict__ Wv, short* __restrict__ wimg)
{
    const int nt = blockIdx.x, kt = blockIdx.y;
    const int z = nt / 6;
    const float* W = (z == 0) ? Wq : (z == 1) ? Wk : Wv;
    const int n0 = (nt - z * 6) * 128;
    short* img = wimg + ((size_t)nt * KT_ + kt) * 8192;
#pragma unroll
    for (int i = 0; i < 4; ++i) {
        const int j = i * 256 + threadIdx.x;
        const int row = j >> 3, kg = j & 7;
        const float* src = W + (size_t)(n0 + row) * HID_ + kt * 64 + kg * 8;
        float4_ f0 = *(const float4_*)src;
        float4_ f1 = *(const float4_*)(src + 4);
        short8 s8;
#pragma unroll
        for (int e = 0; e < 4; ++e) { s8[e] = f2bf(f0[e]); s8[e + 4] = f2bf(f1[e]); }
        *(short8*)(img + ((size_t)kg * 128 + row) * 8) = s8;
    }
}

// ---------------------------------------------------------------------------
// Fused QKV GEMM, register-direct, WIDE wave tile 64x128 (acc 4x8).
// Block tile 128x256 (4 waves: 2 m-halves x 2 B-panels); N-tile 256 aligns
// with the q/k/v split (768 = 3*256). Per phase: 12 loads feed 32 MFMA.
// grid = 1440 flat (XCD-swizzled, mt-major per XCD), block 256.
// ---------------------------------------------------------------------------
__global__ __launch_bounds__(256) void gemm_kernel(
    const short* __restrict__ ximg, const short* __restrict__ wimg,
    const float* __restrict__ bq, const float* __restrict__ bk,
    const float* __restrict__ bv,
    const float* __restrict__ lat, const int* __restrict__ mixw,
    short* __restrict__ qo, short* __restrict__ ko, short* __restrict__ vo)
{
    __shared__ __align__(16) short eP[4][4608];   // per-wave 64x72, 36 KB

    const int bid0 = blockIdx.x;                     // 0..1439
    const int bids = (bid0 & 7) * 180 + (bid0 >> 3); // bijective (1440%8==0)
    const int mt  = bids / 9;          // 0..159  (128-row tiles, b-aligned)
    const int nt9 = bids - mt * 9;     // 0..8    (256-col tiles)

    const int z   = nt9 / 3;                 // 0 q, 1 k, 2 v
    const int nb0 = (nt9 - z * 3) * 256;     // z-local col base: 0/256/512
    const int b   = mt / SB_;
    const int s0  = (mt - b * SB_) * 128;

    const int tid  = threadIdx.x;
    const int wave = tid >> 6;
    const int lane = tid & 63;
    const int quad = lane >> 4;
    const int l16  = lane & 15;
    const int wr   = wave & 1;         // m-half
    const int wc   = wave >> 1;        // B-panel within the 256-col tile

    const short* ag = ximg + (size_t)mt * KT_ * 8192;
    const short* bg = wimg + (size_t)(z * 6 + (nb0 >> 7) + wc) * KT_ * 8192;

    float4_ acc[4][8] = {};
    const int r0 = wr * 64 + l16;

    for (int kt = 0; kt < KT_; ++kt) {
        const short* ak = ag + (size_t)kt * 8192;
        const short* bk8p = bg + (size_t)kt * 8192;
#pragma unroll
        for (int c = 0; c < 2; ++c) {
            const int kb = (c * 4 + quad) * 128;
            short8 af[4], bf[8];
#pragma unroll
            for (int mi = 0; mi < 4; ++mi)
                af[mi] = *(const short8*)(ak + (kb + r0 + mi * 16) * 8);
#pragma unroll
            for (int g = 0; g < 8; ++g)
                bf[g] = *(const short8*)(bk8p + (kb + g * 16 + l16) * 8);
            __builtin_amdgcn_s_setprio(1);
#pragma unroll
            for (int mi = 0; mi < 4; ++mi)
#pragma unroll
                for (int g = 0; g < 8; ++g)
                    acc[mi][g] = __builtin_amdgcn_mfma_f32_16x16x32_bf16(
                        af[mi], bf[g], acc[mi][g], 0, 0, 0);
            __builtin_amdgcn_s_setprio(0);
        }
    }

    // ---- epilogue: two sequential 64x64 head-passes via per-wave scratch ---
    const int mwv = *mixw;
    const float* bb = (z == 0) ? bq : (z == 1) ? bk : bv;
    const int sW = s0 + wr * 64;                      // 64-aligned
    const int ch = sW >> 6;                           // image chunk 0..9
    short* P = eP[wave];
    const int rr = lane >> 3, cc = lane & 7;

#pragma unroll
    for (int hs = 0; hs < 2; ++hs) {
        const int hh = (nb0 >> 6) + wc * 2 + hs;      // z-local head 0..11
        const size_t bh = (size_t)b * NH_ + hh;

        if (z < 2) {
            // row-major: P[s_local][d]
#pragma unroll
            for (int mi = 0; mi < 4; ++mi)
#pragma unroll
                for (int i = 0; i < 4; ++i) {
                    const int ml = mi * 16 + quad * 4 + i;
                    const int s  = sW + ml;
                    const float* lp =
                        lat + (bh * S_ + (s < S_ ? s : S_ - 1)) * HD_;
#pragma unroll
                    for (int gg = 0; gg < 4; ++gg) {
                        const int d = gg * 16 + l16;
                        float val = acc[mi][hs * 4 + gg][i] + bb[hh * 64 + d];
                        if (z == mwv) val *= lp[d];
                        P[ml * 72 + d] = f2bf(val);
                    }
                }
        } else {
            // transposed: P[d][s_local]
#pragma unroll
            for (int mi = 0; mi < 4; ++mi)
#pragma unroll
                for (int gg = 0; gg < 4; ++gg) {
                    const int d  = gg * 16 + l16;
                    const int mb = mi * 16 + quad * 4;
                    short4s w;
#pragma unroll
                    for (int i = 0; i < 4; ++i) {
                        const int s = sW + mb + i;
                        float val = acc[mi][hs * 4 + gg][i] + bb[hh * 64 + d];
                        if (mwv == 2)
                            val *= lat[(bh * S_ + (s < S_ ? s : S_ - 1)) * HD_ + d];
                        w[i] = f2bf(val);
                    }
                    *(short4s*)(P + d * 72 + mb) = w;
                }
        }
        // per-wave scratch: same-wave ds write->read ordering via lgkmcnt

        if (z == 0) {
            short* qb = qo + (size_t)bh * SPAD * HD_;
#pragma unroll
            for (int j = 0; j < 8; ++j) {
                const int r = j * 8 + rr;                 // s_local
                *(short8*)(qb + (size_t)(sW + r) * 64 + cc * 8) =
                    *(const short8*)(P + r * 72 + cc * 8);
            }
        } else if (z == 1) {
            short* kb_ = ko + ((size_t)bh * 10 + ch) * 4096;
#pragma unroll
            for (int j = 0; j < 8; ++j) {
                const int r = j * 8 + rr;                 // s_local
                *(short8*)(kb_ + (cc * 64 + r) * 8) =
                    *(const short8*)(P + r * 72 + cc * 8);
            }
        } else {
            short* vb = vo + ((size_t)bh * 10 + ch) * 4096;
#pragma unroll
            for (int j = 0; j < 8; ++j) {
                const int r = j * 8 + rr;                 // d
                *(short8*)(vb + (cc * 64 + r) * 8) =
                    *(const short8*)(P + r * 72 + cc * 8);
            }
        }
    }
}

// ---------------------------------------------------------------------------
// Flash attention, register-direct K/V streaming, 32 q-rows per wave (two
// 16-row groups share every K/V fragment register -> inflow halved).
// grid = 1920 flat (bh-major per XCD), block 256 (4 waves x 32 q-rows).
// ---------------------------------------------------------------------------
__global__ __launch_bounds__(256) void attn_kernel(
    const short* __restrict__ q, const short* __restrict__ k,
    const short* __restrict__ vt, float* __restrict__ out)
{
    __shared__ __align__(16) short pbuf[4][2][16][64];   // per-wave P, 16 KB

    const int bid0 = blockIdx.x;                      // 0..1919
    const int bids = (bid0 & 7) * 240 + (bid0 >> 3);  // bijective (1920%8==0)
    const int bh = bids / 5;
    const int qt = bids - bh * 5;

    const int b    = bh / NH_;
    const int h    = bh - b * NH_;
    const int tid  = threadIdx.x;
    const int wave = tid >> 6;
    const int lane = tid & 63;
    const int quad = lane >> 4;
    const int l16  = lane & 15;
    const int q0   = qt * 128 + wave * 32;            // wave owns rows q0..q0+31

    const short* qp   = q  + (size_t)bh * SPAD * HD_;
    const short* kimg = k  + (size_t)bh * 40960;
    const short* vimg = vt + (size_t)bh * 40960;

    short8 aq[2][2];
#pragma unroll
    for (int t = 0; t < 2; ++t)
#pragma unroll
        for (int c = 0; c < 2; ++c)
            aq[t][c] = *(const short8*)(qp + (size_t)(q0 + t * 16 + l16) * HD_
                                        + c * 32 + quad * 8);

    float m_i[2][4], l_i[2][4];
    float4_ O[2][4] = {};
#pragma unroll
    for (int t = 0; t < 2; ++t)
#pragma unroll
        for (int i = 0; i < 4; ++i) { m_i[t][i] = -3.0e38f; l_i[t][i] = 0.0f; }

    for (int kc = 0; kc < 10; ++kc) {
        const int key0 = kc * 64;
        const short* Kc = kimg + (size_t)kc * 4096;
        const short* Vc = vimg + (size_t)kc * 4096;

        float4_ sc[2][4] = {};
#pragma unroll
        for (int c = 0; c < 2; ++c) {
            const int kb = (c * 4 + quad) * 64;
            short8 bk8[4];
#pragma unroll
            for (int g = 0; g < 4; ++g)
                bk8[g] = *(const short8*)(Kc + (kb + g * 16 + l16) * 8);
            __builtin_amdgcn_s_setprio(1);
#pragma unroll
            for (int t = 0; t < 2; ++t)
#pragma unroll
                for (int g = 0; g < 4; ++g)
                    sc[t][g] = __builtin_amdgcn_mfma_f32_16x16x32_bf16(
                        aq[t][c], bk8[g], sc[t][g], 0, 0, 0);
            __builtin_amdgcn_s_setprio(0);
        }

        float kmask[4];
#pragma unroll
        for (int g = 0; g < 4; ++g)
            kmask[g] = (key0 + g * 16 + l16 < S_) ? 0.0f : -3.0e38f;

        float alpha[2][4];
#pragma unroll
        for (int t = 0; t < 2; ++t)
#pragma unroll
            for (int i = 0; i < 4; ++i) {
                float s0 = sc[t][0][i] * 0.125f + kmask[0];
                float s1 = sc[t][1][i] * 0.125f + kmask[1];
                float s2 = sc[t][2][i] * 0.125f + kmask[2];
                float s3 = sc[t][3][i] * 0.125f + kmask[3];
                float cm = fmaxf(fmaxf(s0, s1), fmaxf(s2, s3));
#pragma unroll
                for (int off = 1; off < 16; off <<= 1)
                    cm = fmaxf(cm, __shfl_xor(cm, off));
                const float mn = fmaxf(m_i[t][i], cm);
                alpha[t][i] = __expf(m_i[t][i] - mn);
                m_i[t][i] = mn;
                const short p0 = f2bf(__expf(s0 - mn));
                const short p1 = f2bf(__expf(s1 - mn));
                const short p2 = f2bf(__expf(s2 - mn));
                const short p3 = f2bf(__expf(s3 - mn));
                pbuf[wave][t][quad * 4 + i][l16]      = p0;
                pbuf[wave][t][quad * 4 + i][l16 + 16] = p1;
                pbuf[wave][t][quad * 4 + i][l16 + 32] = p2;
                pbuf[wave][t][quad * 4 + i][l16 + 48] = p3;
                float rs = (bf2f(p0) + bf2f(p1)) + (bf2f(p2) + bf2f(p3));
#pragma unroll
                for (int off = 1; off < 16; off <<= 1)
                    rs += __shfl_xor(rs, off);
                l_i[t][i] = l_i[t][i] * alpha[t][i] + rs;
            }

#pragma unroll
        for (int t = 0; t < 2; ++t)
#pragma unroll
            for (int g = 0; g < 4; ++g)
#pragma unroll
                for (int i = 0; i < 4; ++i) O[t][g][i] *= alpha[t][i];

#pragma unroll
        for (int c = 0; c < 2; ++c) {
            const int kb = (c * 4 + quad) * 64;
            short8 bv8[4];
#pragma unroll
            for (int g = 0; g < 4; ++g)
                bv8[g] = *(const short8*)(Vc + (kb + g * 16 + l16) * 8);
            __builtin_amdgcn_s_setprio(1);
#pragma unroll
            for (int t = 0; t < 2; ++t) {
                const short8 ap =
                    *(const short8*)(&pbuf[wave][t][l16][c * 32 + quad * 8]);
#pragma unroll
                for (int g = 0; g < 4; ++g)
                    O[t][g] = __builtin_amdgcn_mfma_f32_16x16x32_bf16(
                        ap, bv8[g], O[t][g], 0, 0, 0);
            }
            __builtin_amdgcn_s_setprio(0);
        }
    }

#pragma unroll
    for (int t = 0; t < 2; ++t)
#pragma unroll
        for (int i = 0; i < 4; ++i) {
            const int s = q0 + t * 16 + quad * 4 + i;
            if (s >= S_) continue;
            const float inv = 1.0f / l_i[t][i];
#pragma unroll
            for (int g = 0; g < 4; ++g)
                out[((size_t)b * S_ + s) * HID_ + h * HD_ + g * 16 + l16] =
                    O[t][g][i] * inv;
        }
}

extern "C" void kernel_launch(void* const* d_in, const int* in_sizes, int n_in,
                              void* d_out, int out_size, void* d_ws, size_t ws_size,
                              hipStream_t stream) {
    (void)in_sizes; (void)n_in; (void)out_size; (void)ws_size;

    const float* X   = (const float*)d_in[0];
    const float* lat = (const float*)d_in[1];
    const float* Wq  = (const float*)d_in[2];
    const float* bq  = (const float*)d_in[3];
    const float* Wk  = (const float*)d_in[4];
    const float* bk  = (const float*)d_in[5];
    const float* Wv  = (const float*)d_in[6];
    const float* bv  = (const float*)d_in[7];
    const int* mixw  = (const int*)d_in[8];
    float* out = (float*)d_out;

    const size_t per = (size_t)B_ * NH_ * SPAD * HD_;   // 15,728,640
    short* qw   = (short*)d_ws;
    short* kw   = qw + per;
    short* vw   = kw + per;
    short* wimg = vw + per;                             // 18*12*8192 = 1,769,472
    short* ximg = wimg + (size_t)NT_ * KT_ * 8192;      // 160*12*8192 = 15,728,640

    convA_kernel<<<dim3(MT_, KT_), 256, 0, stream>>>(X, ximg);
    convB_kernel<<<dim3(NT_, KT_), 256, 0, stream>>>(Wq, Wk, Wv, wimg);
    gemm_kernel<<<dim3(1440), 256, 0, stream>>>(
        ximg, wimg, bq, bk, bv, lat, mixw, qw, kw, vw);
    attn_kernel<<<dim3(1920), 256, 0, stream>>>(qw, kw, vw, out);
}

// Round 5
// 386.924 us; speedup vs baseline: 1.4233x; 1.4233x over previous
//
#include <hip/hip_runtime.h>

#define B_    32
#define S_    577
#define HID_  768
#define NH_   12
#define HD_   64
#define SPAD  640
#define SB_   5            // s-blocks of 128 per batch (5*128 = 640)
#define MT_   160          // b-aligned m-tiles: 32 * 5
#define KT_   12           // 768/64
#define NT_   18           // 2304/128 (B-image panels)

typedef __attribute__((ext_vector_type(8))) short short8;
typedef __attribute__((ext_vector_type(4))) short short4s;
typedef __attribute__((ext_vector_type(4))) float float4_;

static __device__ __forceinline__ float bf2f(short s) {
    union { float f; unsigned u; } cvt;
    cvt.u = ((unsigned)(unsigned short)s) << 16;
    return cvt.f;
}
static __device__ __forceinline__ short f2bf(float f) {
    union { float f; unsigned u; } cvt;
    cvt.f = f;
    unsigned u = cvt.u;
    unsigned r = u + 0x7FFF + ((u >> 16) & 1);   // RNE; finite inputs
    return (short)(r >> 16);
}

// ---------------------------------------------------------------------------
// A image: ximg[mt=b*5+sb][kt][kg8][row128][8]  (MFMA-fragment-ordered bf16)
// ---------------------------------------------------------------------------
__global__ __launch_bounds__(256) void convA_kernel(
    const float* __restrict__ X, short* __restrict__ ximg)
{
    const int mt = blockIdx.x, kt = blockIdx.y;
    const int b = mt / SB_, sb = mt - b * SB_;
    short* img = ximg + ((size_t)mt * KT_ + kt) * 8192;
#pragma unroll
    for (int i = 0; i < 4; ++i) {
        const int j = i * 256 + threadIdx.x;   // 0..1023
        const int row = j >> 3, kg = j & 7;
        const int s = sb * 128 + row;
        const int srow = (s < S_) ? s : 0;     // pad rows: any finite
        const float* src = X + ((size_t)b * S_ + srow) * HID_ + kt * 64 + kg * 8;
        float4_ f0 = *(const float4_*)src;
        float4_ f1 = *(const float4_*)(src + 4);
        short8 s8;
#pragma unroll
        for (int e = 0; e < 4; ++e) { s8[e] = f2bf(f0[e]); s8[e + 4] = f2bf(f1[e]); }
        *(short8*)(img + ((size_t)kg * 128 + row) * 8) = s8;
    }
}

// B image: wimg[nt18][kt][kg8][row128][8], nt = z*6 + local (row = n in tile)
__global__ __launch_bounds__(256) void convB_kernel(
    const float* __restrict__ Wq, const float* __restrict__ Wk,
    const float* __restrict__ Wv, short* __restrict__ wimg)
{
    const int nt = blockIdx.x, kt = blockIdx.y;
    const int z = nt / 6;
    const float* W = (z == 0) ? Wq : (z == 1) ? Wk : Wv;
    const int n0 = (nt - z * 6) * 128;
    short* img = wimg + ((size_t)nt * KT_ + kt) * 8192;
#pragma unroll
    for (int i = 0; i < 4; ++i) {
        const int j = i * 256 + threadIdx.x;
        const int row = j >> 3, kg = j & 7;
        const float* src = W + (size_t)(n0 + row) * HID_ + kt * 64 + kg * 8;
        float4_ f0 = *(const float4_*)src;
        float4_ f1 = *(const float4_*)(src + 4);
        short8 s8;
#pragma unroll
        for (int e = 0; e < 4; ++e) { s8[e] = f2bf(f0[e]); s8[e + 4] = f2bf(f1[e]); }
        *(short8*)(img + ((size_t)kg * 128 + row) * 8) = s8;
    }
}

// ---------------------------------------------------------------------------
// Fused QKV GEMM, register-direct fragment streaming (R3 verbatim — best
// measured: 163.6 us). 64x64 wave tiles, no staging LDS, no barriers.
// grid = 2880 flat (XCD-swizzled, mt-major per XCD), block 256 (4 waves).
// ---------------------------------------------------------------------------
__global__ __launch_bounds__(256) void gemm_kernel(
    const short* __restrict__ ximg, const short* __restrict__ wimg,
    const float* __restrict__ bq, const float* __restrict__ bk,
    const float* __restrict__ bv,
    const float* __restrict__ lat, const int* __restrict__ mixw,
    short* __restrict__ qo, short* __restrict__ ko, short* __restrict__ vo)
{
    __shared__ __align__(16) short eP[4][4608];   // per-wave 64x72, 36 KB

    const int bid0 = blockIdx.x;                     // 0..2879
    const int bids = (bid0 & 7) * 360 + (bid0 >> 3); // bijective (2880%8==0)
    const int mt = bids / NT_;
    const int nt = bids - mt * NT_;

    const int z   = nt / 6;
    const int nz0 = (nt - z * 6) * 128;
    const int b   = mt / SB_;
    const int s0  = (mt - b * SB_) * 128;

    const int tid  = threadIdx.x;
    const int wave = tid >> 6;
    const int lane = tid & 63;
    const int quad = lane >> 4;
    const int l16  = lane & 15;

    const short* ag = ximg + ((size_t)mt * KT_) * 8192;
    const short* bg = wimg + ((size_t)nt * KT_) * 8192;

    float4_ acc[4][4] = {};
    const int r0 = (wave & 1) * 64 + l16;
    const int c0 = (wave >> 1) * 64 + l16;

    for (int kt = 0; kt < KT_; ++kt) {
        const short* ak = ag + (size_t)kt * 8192;
        const short* bk8p = bg + (size_t)kt * 8192;
#pragma unroll
        for (int c = 0; c < 2; ++c) {
            const int kb = (c * 4 + quad) * 128;
            short8 af[4], bf4[4];
#pragma unroll
            for (int mi = 0; mi < 4; ++mi)
                af[mi] = *(const short8*)(ak + (kb + r0 + mi * 16) * 8);
#pragma unroll
            for (int g = 0; g < 4; ++g)
                bf4[g] = *(const short8*)(bk8p + (kb + c0 + g * 16) * 8);
            __builtin_amdgcn_s_setprio(1);
#pragma unroll
            for (int mi = 0; mi < 4; ++mi)
#pragma unroll
                for (int g = 0; g < 4; ++g)
                    acc[mi][g] = __builtin_amdgcn_mfma_f32_16x16x32_bf16(
                        af[mi], bf4[g], acc[mi][g], 0, 0, 0);
            __builtin_amdgcn_s_setprio(0);
        }
    }

    // -------- epilogue via per-wave LDS scratch, coalesced 16B stores -------
    const int mwv = *mixw;
    const float* bb = (z == 0) ? bq : (z == 1) ? bk : bv;
    const int hh   = (nz0 + (wave >> 1) * 64) >> 6;       // head 0..11
    const size_t bh = (size_t)b * NH_ + hh;
    const int sW   = s0 + (wave & 1) * 64;                // 64-aligned
    const int ch   = sW >> 6;                             // image chunk 0..9
    short* P = eP[wave];

    if (z < 2) {
        // row-major: P[s_local][d]
#pragma unroll
        for (int mi = 0; mi < 4; ++mi)
#pragma unroll
            for (int i = 0; i < 4; ++i) {
                const int ml = mi * 16 + quad * 4 + i;
                const int s  = sW + ml;
                const float* lp =
                    lat + (bh * S_ + (s < S_ ? s : S_ - 1)) * HD_;
#pragma unroll
                for (int g = 0; g < 4; ++g) {
                    const int d = g * 16 + l16;
                    float val = acc[mi][g][i] + bb[hh * 64 + d];
                    if (z == mwv) val *= lp[d];
                    P[ml * 72 + d] = f2bf(val);
                }
            }
    } else {
        // transposed: P[d][s_local]
#pragma unroll
        for (int mi = 0; mi < 4; ++mi)
#pragma unroll
            for (int g = 0; g < 4; ++g) {
                const int d  = g * 16 + l16;
                const int mb = mi * 16 + quad * 4;
                short4s w;
#pragma unroll
                for (int i = 0; i < 4; ++i) {
                    const int s = sW + mb + i;
                    float val = acc[mi][g][i] + bb[hh * 64 + d];
                    if (mwv == 2)
                        val *= lat[(bh * S_ + (s < S_ ? s : S_ - 1)) * HD_ + d];
                    w[i] = f2bf(val);
                }
                *(short4s*)(P + d * 72 + mb) = w;
            }
    }
    // per-wave scratch: same-wave ds write->read ordering via lgkmcnt

    const int rr = lane >> 3, cc = lane & 7;
    if (z == 0) {
        short* qb = qo + (size_t)bh * SPAD * HD_;
#pragma unroll
        for (int j = 0; j < 8; ++j) {
            const int r = j * 8 + rr;                     // s_local
            *(short8*)(qb + (size_t)(sW + r) * 64 + cc * 8) =
                *(const short8*)(P + r * 72 + cc * 8);
        }
    } else if (z == 1) {
        short* kb_ = ko + ((size_t)bh * 10 + ch) * 4096;
#pragma unroll
        for (int j = 0; j < 8; ++j) {
            const int r = j * 8 + rr;                     // s_local
            *(short8*)(kb_ + (cc * 64 + r) * 8) =
                *(const short8*)(P + r * 72 + cc * 8);
        }
    } else {
        short* vb = vo + ((size_t)bh * 10 + ch) * 4096;
#pragma unroll
        for (int j = 0; j < 8; ++j) {
            const int r = j * 8 + rr;                     // d
            *(short8*)(vb + (cc * 64 + r) * 8) =
                *(const short8*)(P + r * 72 + cc * 8);
        }
    }
}

// ---------------------------------------------------------------------------
// Flash attention with SWAPPED QK^T (mfma(K,Q)): q-row = lane&15 per lane, so
// softmax row-reduce is 15 in-register fmax/adds + 2 shfl_xor (vs 32 shuffles)
// and m/l are per-lane scalars. P goes to LDS as 4 packed ds_write_b64 into an
// XOR-swizzled pbuf (conflict-optimal b128 reads for PV). Register-direct K/V
// streaming, no barriers. grid = 3840 flat (bh-major per XCD), block 256.
// ---------------------------------------------------------------------------
__global__ __launch_bounds__(256) void attn_kernel(
    const short* __restrict__ q, const short* __restrict__ k,
    const short* __restrict__ vt, float* __restrict__ out)
{
    __shared__ __align__(16) short pbuf[4][16][64];   // per-wave P, 8 KB

    const int bid0 = blockIdx.x;                      // 0..3839
    const int bids = (bid0 & 7) * 480 + (bid0 >> 3);  // bijective (3840%8==0)
    const int bh = bids / 10;
    const int qt = bids - bh * 10;

    const int b    = bh / NH_;
    const int h    = bh - b * NH_;
    const int tid  = threadIdx.x;
    const int wave = tid >> 6;
    const int lane = tid & 63;
    const int quad = lane >> 4;
    const int l16  = lane & 15;
    const int q0   = qt * 64 + wave * 16;

    const short* qp   = q  + (size_t)bh * SPAD * HD_;
    const short* kimg = k  + (size_t)bh * 40960;
    const short* vimg = vt + (size_t)bh * 40960;

    // Q fragment (used as the MFMA *B* operand; layout identical to A)
    const short8 aq0 = *(const short8*)(qp + (size_t)(q0 + l16) * HD_ + quad * 8);
    const short8 aq1 = *(const short8*)(qp + (size_t)(q0 + l16) * HD_ + 32 + quad * 8);

    // per-lane softmax state for q-row (q0 + l16), replicated across quads
    float m_i = -3.0e38f, l_i = 0.0f;
    float4_ O[4] = {};

    // swizzled pbuf addressing: row = l16, key-byte x -> x ^ ((l16&7)<<4)
    char* pw = (char*)&pbuf[wave][l16][0];
    const int swz = (l16 & 7) << 4;

    for (int kc = 0; kc < 10; ++kc) {
        const short* Kc = kimg + (size_t)kc * 4096;
        const short* Vc = vimg + (size_t)kc * 4096;

        // ---- QK^T swapped: sc[g] rows = keys (g*16 + quad*4 + i), col = l16
        float4_ sc[4] = {};
#pragma unroll
        for (int c = 0; c < 2; ++c) {
            const int kb = (c * 4 + quad) * 64;
            const short8 aq = c ? aq1 : aq0;
            short8 kf[4];
#pragma unroll
            for (int g = 0; g < 4; ++g)
                kf[g] = *(const short8*)(Kc + (kb + g * 16 + l16) * 8);
            __builtin_amdgcn_s_setprio(1);
#pragma unroll
            for (int g = 0; g < 4; ++g)
                sc[g] = __builtin_amdgcn_mfma_f32_16x16x32_bf16(kf[g], aq, sc[g], 0, 0, 0);
            __builtin_amdgcn_s_setprio(0);
        }

        if (kc == 9) {  // tail mask: keys 576..639, only 576 valid
#pragma unroll
            for (int g = 0; g < 4; ++g)
#pragma unroll
                for (int i = 0; i < 4; ++i)
                    if (576 + g * 16 + quad * 4 + i >= S_) sc[g][i] = -3.0e38f;
        }

        // ---- row max: 15 in-register + 2 cross-quad shuffles
        float cm = sc[0][0];
#pragma unroll
        for (int g = 0; g < 4; ++g)
#pragma unroll
            for (int i = 0; i < 4; ++i) cm = fmaxf(cm, sc[g][i]);
        cm = fmaxf(cm, __shfl_xor(cm, 16));
        cm = fmaxf(cm, __shfl_xor(cm, 32));

        const float mn    = fmaxf(m_i, cm);
        const float alpha = __expf((m_i - mn) * 0.125f);
        m_i = mn;
        const float mo = mn * 0.125f;

        // ---- P = exp(s*0.125 - mo), pack to bf16, swizzled b64 stores, sum
        float rs = 0.0f;
#pragma unroll
        for (int g = 0; g < 4; ++g) {
            short4s w;
#pragma unroll
            for (int i = 0; i < 4; ++i) {
                const float p = __expf(__builtin_fmaf(sc[g][i], 0.125f, -mo));
                const short pb = f2bf(p);
                w[i] = pb;
                rs += bf2f(pb);
            }
            *(short4s*)(pw + ((g * 32 + quad * 8) ^ swz)) = w;
        }
        rs += __shfl_xor(rs, 16);
        rs += __shfl_xor(rs, 32);
        l_i = l_i * alpha + rs;

        // ---- gather alpha for O rows (row = quad*4+i lives at lane l16=row)
        float av[4];
#pragma unroll
        for (int i = 0; i < 4; ++i)
            av[i] = __shfl(alpha, quad * 20 + i);   // lane quad*16 + (quad*4+i)
#pragma unroll
        for (int g = 0; g < 4; ++g)
#pragma unroll
            for (int i = 0; i < 4; ++i) O[g][i] *= av[i];

        // ---- PV: A = P (row = l16, keys c*32+quad*8..+8), B = V fragments
#pragma unroll
        for (int c = 0; c < 2; ++c) {
            const short8 ap =
                *(const short8*)(pw + ((c * 64 + quad * 16) ^ swz));
            const int kb = (c * 4 + quad) * 64;
            short8 vf[4];
#pragma unroll
            for (int g = 0; g < 4; ++g)
                vf[g] = *(const short8*)(Vc + (kb + g * 16 + l16) * 8);
            __builtin_amdgcn_s_setprio(1);
#pragma unroll
            for (int g = 0; g < 4; ++g)
                O[g] = __builtin_amdgcn_mfma_f32_16x16x32_bf16(ap, vf[g], O[g], 0, 0, 0);
            __builtin_amdgcn_s_setprio(0);
        }
    }

    // ---- epilogue: O row = quad*4+i, col d = g*16+l16; gather 1/l per row
    float linv[4];
#pragma unroll
    for (int i = 0; i < 4; ++i)
        linv[i] = 1.0f / __shfl(l_i, quad * 20 + i);
#pragma unroll
    for (int i = 0; i < 4; ++i) {
        const int s = q0 + quad * 4 + i;
        if (s >= S_) continue;
#pragma unroll
        for (int g = 0; g < 4; ++g)
            out[((size_t)b * S_ + s) * HID_ + h * HD_ + g * 16 + l16] =
                O[g][i] * linv[i];
    }
}

extern "C" void kernel_launch(void* const* d_in, const int* in_sizes, int n_in,
                              void* d_out, int out_size, void* d_ws, size_t ws_size,
                              hipStream_t stream) {
    (void)in_sizes; (void)n_in; (void)out_size; (void)ws_size;

    const float* X   = (const float*)d_in[0];
    const float* lat = (const float*)d_in[1];
    const float* Wq  = (const float*)d_in[2];
    const float* bq  = (const float*)d_in[3];
    const float* Wk  = (const float*)d_in[4];
    const float* bk  = (const float*)d_in[5];
    const float* Wv  = (const float*)d_in[6];
    const float* bv  = (const float*)d_in[7];
    const int* mixw  = (const int*)d_in[8];
    float* out = (float*)d_out;

    const size_t per = (size_t)B_ * NH_ * SPAD * HD_;   // 15,728,640
    short* qw   = (short*)d_ws;
    short* kw   = qw + per;
    short* vw   = kw + per;
    short* wimg = vw + per;                             // 18*12*8192 = 1,769,472
    short* ximg = wimg + (size_t)NT_ * KT_ * 8192;      // 160*12*8192 = 15,728,640

    convA_kernel<<<dim3(MT_, KT_), 256, 0, stream>>>(X, ximg);
    convB_kernel<<<dim3(NT_, KT_), 256, 0, stream>>>(Wq, Wk, Wv, wimg);
    gemm_kernel<<<dim3(2880), 256, 0, stream>>>(
        ximg, wimg, bq, bk, bv, lat, mixw, qw, kw, vw);
    attn_kernel<<<dim3(3840), 256, 0, stream>>>(qw, kw, vw, out);
}